// Round 8
// baseline (1674.401 us; speedup 1.0000x reference)
//
#include <hip/hip_runtime.h>

#define T_TOK 2048
#define H_DIM 2048
#define F_DIM 7168
#define E_NUM 8
#define MAX_SLOTS 5120   // 4096 used slots + per-expert pad to 128

typedef __attribute__((ext_vector_type(8))) _Float16 f16x8;
typedef __attribute__((ext_vector_type(4))) float    f32x4;

// async global->LDS, 16B per lane; LDS dest wave-uniform base + lane*16
#define GLL(g, l) __builtin_amdgcn_global_load_lds(                          \
    (const __attribute__((address_space(1))) void*)(g),                      \
    (__attribute__((address_space(3))) void*)(l), 16, 0, 0)

// ---------------- small kernels ----------------

// fp32 -> fp16 bulk convert (hidden states only)
__global__ __launch_bounds__(256) void cvtx_kernel(const float* __restrict__ src,
                                                   _Float16* __restrict__ dst) {
    size_t i = ((size_t)blockIdx.x * 256 + threadIdx.x) * 8;
    float4 a = *(const float4*)(src + i);
    float4 b = *(const float4*)(src + i + 4);
    f16x8 h;
    h[0]=(_Float16)a.x; h[1]=(_Float16)a.y; h[2]=(_Float16)a.z; h[3]=(_Float16)a.w;
    h[4]=(_Float16)b.x; h[5]=(_Float16)b.y; h[6]=(_Float16)b.z; h[7]=(_Float16)b.w;
    *(f16x8*)(dst + i) = h;
}

__global__ __launch_bounds__(256) void router_kernel(
    const float* __restrict__ x, const float* __restrict__ wg,
    float* __restrict__ logits_out, int* __restrict__ tk_e,
    float* __restrict__ tk_w, int* __restrict__ meta) {
    int wave = threadIdx.x >> 6;
    int lane = threadIdx.x & 63;
    int t = blockIdx.x * 4 + wave;
    const float* xr = x + (size_t)t * H_DIM;

    float xv[32];
#pragma unroll
    for (int i = 0; i < 8; i++) {
        float4 v = *(const float4*)(xr + i * 256 + lane * 4);
        xv[i*4+0] = v.x; xv[i*4+1] = v.y; xv[i*4+2] = v.z; xv[i*4+3] = v.w;
    }
    float lg[E_NUM];
#pragma unroll
    for (int e = 0; e < E_NUM; e++) {
        const float* wr = wg + (size_t)e * H_DIM;
        float acc = 0.f;
#pragma unroll
        for (int i = 0; i < 8; i++) {
            float4 v = *(const float4*)(wr + i * 256 + lane * 4);
            acc += xv[i*4+0]*v.x + xv[i*4+1]*v.y + xv[i*4+2]*v.z + xv[i*4+3]*v.w;
        }
#pragma unroll
        for (int s = 32; s > 0; s >>= 1) acc += __shfl_xor(acc, s, 64);
        lg[e] = acc;
    }
    if (lane == 0) {
        float b0 = -3e38f, b1 = -3e38f; int i0 = 0, i1 = 0;
#pragma unroll
        for (int e = 0; e < E_NUM; e++) {
            float le = lg[e];
            if (le > b0)      { b1 = b0; i1 = i0; b0 = le; i0 = e; }
            else if (le > b1) { b1 = le; i1 = e; }
        }
        float w0 = 1.f / (1.f + __expf(b1 - b0));
        float w1v = 1.f - w0;
#pragma unroll
        for (int e = 0; e < E_NUM; e++) logits_out[(size_t)t * E_NUM + e] = lg[e];
        tk_e[t*2+0] = i0; tk_w[t*2+0] = w0;
        tk_e[t*2+1] = i1; tk_w[t*2+1] = w1v;
        atomicAdd(&meta[i0], 1);
        atomicAdd(&meta[i1], 1);
    }
}

// meta layout: [0..7]=cnt, [8..15]=cnt_pad128, [16..23]=base, [24..31]=fill
__global__ void scan_kernel(int* __restrict__ meta, int* __restrict__ slot_tok,
                            float* __restrict__ slot_w) {
    int lane = threadIdx.x;  // 64 threads
    int cnts[E_NUM], pads[E_NUM], bases[E_NUM];
    int run = 0;
#pragma unroll
    for (int e = 0; e < E_NUM; e++) {
        cnts[e] = meta[e];
        pads[e] = (cnts[e] + 127) & ~127;
        bases[e] = run;
        run += pads[e];
    }
    if (lane < E_NUM) { meta[8 + lane] = pads[lane]; meta[16 + lane] = bases[lane]; }
    for (int e = 0; e < E_NUM; e++)
        for (int i = cnts[e] + lane; i < pads[e]; i += 64) {
            slot_tok[bases[e] + i] = 0;
            slot_w[bases[e] + i] = 0.f;
        }
}

__global__ __launch_bounds__(256) void assign_kernel(
    const int* __restrict__ tk_e, const float* __restrict__ tk_w,
    int* __restrict__ meta, int* __restrict__ slot_tok, float* __restrict__ slot_w) {
    int t = blockIdx.x * 256 + threadIdx.x;
    if (t >= T_TOK) return;
#pragma unroll
    for (int k = 0; k < 2; k++) {
        int e = tk_e[t*2+k];
        int pos = atomicAdd(&meta[24 + e], 1);
        int s = meta[16 + e] + pos;
        slot_tok[s] = t;
        slot_w[s] = tk_w[t*2+k];
    }
}

// ============ fused-convert grouped GEMM, 128x128xK64, dbuf, 1 barrier/tile ============
// 4 waves 2Mx2N (64x64 each). A fp16 via GLL (source pre-swizzled, 1 tile ahead,
// counted vmcnt(12)); B fp32 reg-staged (loaded 1 tile ahead, cvt+swizzled ds_write
// after compute). LDS 64 KB -> 2 blocks/CU; TLP + counted vmcnt hide latency.

// ---------------- ffn1: B-rows 0..127 = interleaved w1/w3 (64 f-cols) ----------------
__global__ void ffn1_kernel(
    const _Float16* __restrict__ xb, const float* __restrict__ w1,
    const float* __restrict__ w3, const int* __restrict__ slot_tok,
    const int* __restrict__ meta, _Float16* __restrict__ hbuf) {
    int e = blockIdx.z;
    int cntpad = meta[8 + e];
    int mb = blockIdx.y;
    if (mb * 128 >= cntpad) return;
    int base = meta[16 + e];
    int nb = blockIdx.x;                 // 0..111, 64 f-cols each

    __shared__ _Float16 sA[2][128][64];  // 32 KB
    __shared__ _Float16 sB[2][128][64];  // 32 KB

    int tid  = threadIdx.x;
    int lane = tid & 63;
    int wave = tid >> 6;                 // 0..3
    int wm = wave >> 1, wn = wave & 1;   // 2(M) x 2(N), 64x64 per wave
    int lr  = lane & 15;
    int sg  = lane >> 4;
    int sw7 = lane & 7;
    int so0 = ((sg    ) ^ sw7) * 8;      // swizzled 16B-slot (half units), k-half 0
    int so1 = ((sg + 4) ^ sw7) * 8;      // k-half 1

    // ---- A staging (GLL): wave covers rows wave*32 + c*8 + rsub, source pre-swizzled
    int rsub = lane >> 3;
    int sl   = sw7 ^ rsub;
    const _Float16* aP[4];
#pragma unroll
    for (int c = 0; c < 4; c++) {
        int row = wave * 32 + c * 8 + rsub;
        int tok = slot_tok[base + mb * 128 + row];
        aP[c] = xb + (size_t)tok * H_DIM + sl * 8;
    }

    // ---- B staging (fp32 regs): brow = tid>>1, kh = tid&1 (32 floats each)
    // rows [q64*64 .. q64*64+31] = w1 f=nb*64+q64*32+sub, [+32..63] = w3 same f
    int brow = tid >> 1;
    int kh   = tid & 1;
    int q64  = brow >> 6;
    int sub  = brow & 63;
    const float* wsel = (sub < 32) ? w1 : w3;
    const float* bsrc = wsel + ((size_t)e * F_DIM + (size_t)nb * 64
                                + (size_t)q64 * 32 + (sub & 31)) * H_DIM + kh * 32;
    int bwr[4];
#pragma unroll
    for (int q = 0; q < 4; q++)
        bwr[q] = brow * 128 + (((kh * 4 + q) ^ (brow & 7)) * 16);

    f32x4 zero = {0.f, 0.f, 0.f, 0.f};
    f32x4 acc[4][4];
#pragma unroll
    for (int m = 0; m < 4; m++)
#pragma unroll
        for (int n = 0; n < 4; n++) acc[m][n] = zero;

    const int NT = H_DIM / 64;  // 32
    float4 brg[8];

    // ---- prologue: tile 0
#pragma unroll
    for (int q = 0; q < 8; q++) brg[q] = *(const float4*)(bsrc + q * 4);
#pragma unroll
    for (int c = 0; c < 4; c++) GLL(aP[c], &sA[0][wave * 32 + c * 8][0]);
    {
        char* sBc = (char*)&sB[0][0][0];
#pragma unroll
        for (int q = 0; q < 4; q++) {
            float4 a = brg[2*q], b = brg[2*q+1];
            f16x8 p;
            p[0]=(_Float16)a.x; p[1]=(_Float16)a.y; p[2]=(_Float16)a.z; p[3]=(_Float16)a.w;
            p[4]=(_Float16)b.x; p[5]=(_Float16)b.y; p[6]=(_Float16)b.z; p[7]=(_Float16)b.w;
            *(f16x8*)(void*)(sBc + bwr[q]) = p;
        }
    }
    asm volatile("s_waitcnt lgkmcnt(0)" ::: "memory");
    __builtin_amdgcn_s_barrier();

    for (int t = 0; t < NT; ++t) {
        int cur = t & 1, nxt = cur ^ 1;
        // issue next tile's loads FIRST (br then GLL), then counted wait on GLL(t)
        if (t + 1 < NT) {
            int k = (t + 1) * 64;
#pragma unroll
            for (int q = 0; q < 8; q++) brg[q] = *(const float4*)(bsrc + k + q * 4);
#pragma unroll
            for (int c = 0; c < 4; c++) GLL(aP[c] + k, &sA[nxt][wave * 32 + c * 8][0]);
            asm volatile("s_waitcnt vmcnt(12)" ::: "memory");   // GLL(t) complete
        } else {
            asm volatile("s_waitcnt vmcnt(0)" ::: "memory");
        }
        __builtin_amdgcn_sched_barrier(0);

        const _Float16* Ab = &sA[cur][wm * 64][0];
        const _Float16* Bb = &sB[cur][wn * 64][0];
        __builtin_amdgcn_s_setprio(1);
        {
            f16x8 a0[4], b0[4];
#pragma unroll
            for (int n = 0; n < 4; n++) b0[n] = *(const f16x8*)(const void*)(Bb + n * 1024 + lr * 64 + so0);
#pragma unroll
            for (int m = 0; m < 4; m++) a0[m] = *(const f16x8*)(const void*)(Ab + m * 1024 + lr * 64 + so0);
#pragma unroll
            for (int m = 0; m < 4; m++)
#pragma unroll
                for (int n = 0; n < 4; n++)
                    acc[m][n] = __builtin_amdgcn_mfma_f32_16x16x32_f16(a0[m], b0[n], acc[m][n], 0, 0, 0);
            f16x8 a1[4], b1[4];
#pragma unroll
            for (int n = 0; n < 4; n++) b1[n] = *(const f16x8*)(const void*)(Bb + n * 1024 + lr * 64 + so1);
#pragma unroll
            for (int m = 0; m < 4; m++) a1[m] = *(const f16x8*)(const void*)(Ab + m * 1024 + lr * 64 + so1);
#pragma unroll
            for (int m = 0; m < 4; m++)
#pragma unroll
                for (int n = 0; n < 4; n++)
                    acc[m][n] = __builtin_amdgcn_mfma_f32_16x16x32_f16(a1[m], b1[n], acc[m][n], 0, 0, 0);
        }
        __builtin_amdgcn_s_setprio(0);
        __builtin_amdgcn_sched_barrier(0);   // keep cvt/ds_write AFTER the MFMAs

        if (t + 1 < NT) {                    // write B(t+1) (compiler waits br loads)
            char* sBc = (char*)&sB[nxt][0][0];
#pragma unroll
            for (int q = 0; q < 4; q++) {
                float4 a = brg[2*q], b = brg[2*q+1];
                f16x8 p;
                p[0]=(_Float16)a.x; p[1]=(_Float16)a.y; p[2]=(_Float16)a.z; p[3]=(_Float16)a.w;
                p[4]=(_Float16)b.x; p[5]=(_Float16)b.y; p[6]=(_Float16)b.z; p[7]=(_Float16)b.w;
                *(f16x8*)(void*)(sBc + bwr[q]) = p;
            }
        }
        asm volatile("s_waitcnt lgkmcnt(0)" ::: "memory");
        __builtin_amdgcn_s_barrier();
    }

    // epilogue: pairs (n, n+2) = (w1, w3) same f; f = nb*64 + wn*32 + n*16 + lr
    int fb = nb * 64 + wn * 32;
#pragma unroll
    for (int m = 0; m < 4; m++) {
#pragma unroll
        for (int j = 0; j < 4; j++) {
            int re = mb * 128 + wm * 64 + m * 16 + sg * 4 + j;
            size_t srow = (size_t)(base + re) * F_DIM;
#pragma unroll
            for (int p = 0; p < 2; p++) {
                float a1v = acc[m][p][j], a3v = acc[m][p + 2][j];
                float hv = a1v * a3v / (1.f + __expf(-a1v));
                hbuf[srow + fb + p * 16 + lr] = (_Float16)hv;
            }
        }
    }
}

// ---------------- ffn2: A = hbuf fp16 (GLL), B = w2 fp32 reg-staged ----------------
__global__ void ffn2_kernel(
    const _Float16* __restrict__ hbuf, const float* __restrict__ w2,
    const int* __restrict__ slot_tok, const float* __restrict__ slot_w,
    const int* __restrict__ meta, float* __restrict__ out) {
    int e = blockIdx.z;
    int cntpad = meta[8 + e];
    int mb = blockIdx.y;
    if (mb * 128 >= cntpad) return;
    int base = meta[16 + e];
    int nb = blockIdx.x;                 // 0..15, 128 H-cols each

    __shared__ _Float16 sA[2][128][64];
    __shared__ _Float16 sB[2][128][64];

    int tid  = threadIdx.x;
    int lane = tid & 63;
    int wave = tid >> 6;
    int wm = wave >> 1, wn = wave & 1;
    int lr  = lane & 15;
    int sg  = lane >> 4;
    int sw7 = lane & 7;
    int so0 = ((sg    ) ^ sw7) * 8;
    int so1 = ((sg + 4) ^ sw7) * 8;

    int rsub = lane >> 3;
    int sl   = sw7 ^ rsub;
    const _Float16* aP[4];
#pragma unroll
    for (int c = 0; c < 4; c++) {
        int row = wave * 32 + c * 8 + rsub;
        aP[c] = hbuf + (size_t)(base + mb * 128 + row) * F_DIM + sl * 8;
    }

    int brow = tid >> 1;
    int kh   = tid & 1;
    const float* bsrc = w2 + ((size_t)e * H_DIM + (size_t)nb * 128 + brow) * F_DIM + kh * 32;
    int bwr[4];
#pragma unroll
    for (int q = 0; q < 4; q++)
        bwr[q] = brow * 128 + (((kh * 4 + q) ^ (brow & 7)) * 16);

    f32x4 zero = {0.f, 0.f, 0.f, 0.f};
    f32x4 acc[4][4];
#pragma unroll
    for (int m = 0; m < 4; m++)
#pragma unroll
        for (int n = 0; n < 4; n++) acc[m][n] = zero;

    const int NT = F_DIM / 64;  // 112
    float4 brg[8];

#pragma unroll
    for (int q = 0; q < 8; q++) brg[q] = *(const float4*)(bsrc + q * 4);
#pragma unroll
    for (int c = 0; c < 4; c++) GLL(aP[c], &sA[0][wave * 32 + c * 8][0]);
    {
        char* sBc = (char*)&sB[0][0][0];
#pragma unroll
        for (int q = 0; q < 4; q++) {
            float4 a = brg[2*q], b = brg[2*q+1];
            f16x8 p;
            p[0]=(_Float16)a.x; p[1]=(_Float16)a.y; p[2]=(_Float16)a.z; p[3]=(_Float16)a.w;
            p[4]=(_Float16)b.x; p[5]=(_Float16)b.y; p[6]=(_Float16)b.z; p[7]=(_Float16)b.w;
            *(f16x8*)(void*)(sBc + bwr[q]) = p;
        }
    }
    asm volatile("s_waitcnt lgkmcnt(0)" ::: "memory");
    __builtin_amdgcn_s_barrier();

    for (int t = 0; t < NT; ++t) {
        int cur = t & 1, nxt = cur ^ 1;
        if (t + 1 < NT) {
            int k = (t + 1) * 64;
#pragma unroll
            for (int q = 0; q < 8; q++) brg[q] = *(const float4*)(bsrc + k + q * 4);
#pragma unroll
            for (int c = 0; c < 4; c++) GLL(aP[c] + k, &sA[nxt][wave * 32 + c * 8][0]);
            asm volatile("s_waitcnt vmcnt(12)" ::: "memory");
        } else {
            asm volatile("s_waitcnt vmcnt(0)" ::: "memory");
        }
        __builtin_amdgcn_sched_barrier(0);

        const _Float16* Ab = &sA[cur][wm * 64][0];
        const _Float16* Bb = &sB[cur][wn * 64][0];
        __builtin_amdgcn_s_setprio(1);
        {
            f16x8 a0[4], b0[4];
#pragma unroll
            for (int n = 0; n < 4; n++) b0[n] = *(const f16x8*)(const void*)(Bb + n * 1024 + lr * 64 + so0);
#pragma unroll
            for (int m = 0; m < 4; m++) a0[m] = *(const f16x8*)(const void*)(Ab + m * 1024 + lr * 64 + so0);
#pragma unroll
            for (int m = 0; m < 4; m++)
#pragma unroll
                for (int n = 0; n < 4; n++)
                    acc[m][n] = __builtin_amdgcn_mfma_f32_16x16x32_f16(a0[m], b0[n], acc[m][n], 0, 0, 0);
            f16x8 a1[4], b1[4];
#pragma unroll
            for (int n = 0; n < 4; n++) b1[n] = *(const f16x8*)(const void*)(Bb + n * 1024 + lr * 64 + so1);
#pragma unroll
            for (int m = 0; m < 4; m++) a1[m] = *(const f16x8*)(const void*)(Ab + m * 1024 + lr * 64 + so1);
#pragma unroll
            for (int m = 0; m < 4; m++)
#pragma unroll
                for (int n = 0; n < 4; n++)
                    acc[m][n] = __builtin_amdgcn_mfma_f32_16x16x32_f16(a1[m], b1[n], acc[m][n], 0, 0, 0);
        }
        __builtin_amdgcn_s_setprio(0);
        __builtin_amdgcn_sched_barrier(0);

        if (t + 1 < NT) {
            char* sBc = (char*)&sB[nxt][0][0];
#pragma unroll
            for (int q = 0; q < 4; q++) {
                float4 a = brg[2*q], b = brg[2*q+1];
                f16x8 p;
                p[0]=(_Float16)a.x; p[1]=(_Float16)a.y; p[2]=(_Float16)a.z; p[3]=(_Float16)a.w;
                p[4]=(_Float16)b.x; p[5]=(_Float16)b.y; p[6]=(_Float16)b.z; p[7]=(_Float16)b.w;
                *(f16x8*)(void*)(sBc + bwr[q]) = p;
            }
        }
        asm volatile("s_waitcnt lgkmcnt(0)" ::: "memory");
        __builtin_amdgcn_s_barrier();
    }

    int row0 = mb * 128 + wm * 64;
    int col0 = nb * 128 + wn * 64;
#pragma unroll
    for (int m = 0; m < 4; m++) {
        int rbw = row0 + m * 16 + sg * 4;
        int toks[4]; float wts[4];
#pragma unroll
        for (int j = 0; j < 4; j++) {
            int s = base + rbw + j;
            toks[j] = slot_tok[s];
            wts[j]  = slot_w[s];
        }
#pragma unroll
        for (int n = 0; n < 4; n++) {
            int col = col0 + n * 16 + lr;
            f32x4 v = acc[m][n];
#pragma unroll
            for (int j = 0; j < 4; j++)
                atomicAdd(&out[(size_t)toks[j] * H_DIM + col], v[j] * wts[j]);
        }
    }
}

// ---------------- launcher ----------------
extern "C" void kernel_launch(void* const* d_in, const int* in_sizes, int n_in,
                              void* d_out, int out_size, void* d_ws, size_t ws_size,
                              hipStream_t stream) {
    const float* x  = (const float*)d_in[0];
    const float* wg = (const float*)d_in[1];
    const float* w1 = (const float*)d_in[2];
    const float* w3 = (const float*)d_in[3];
    const float* w2 = (const float*)d_in[4];
    float* out = (float*)d_out;
    float* logits = out + (size_t)T_TOK * H_DIM;

    char* ws = (char*)d_ws;
    _Float16* hbuf = (_Float16*)ws;                       // 70 MiB
    _Float16* xb   = hbuf + (size_t)MAX_SLOTS * F_DIM;    // 8 MiB
    char* p = (char*)(xb + (size_t)T_TOK * H_DIM);
    int*   slot_tok = (int*)p;   p += MAX_SLOTS * 4;
    float* slot_w   = (float*)p; p += MAX_SLOTS * 4;
    int*   tk_e     = (int*)p;   p += T_TOK * 2 * 4;
    float* tk_w     = (float*)p; p += T_TOK * 2 * 4;
    int*   meta     = (int*)p;   // 32 ints

    hipMemsetAsync(d_out, 0, (size_t)out_size * sizeof(float), stream);
    hipMemsetAsync(meta, 0, 32 * sizeof(int), stream);

    cvtx_kernel<<<dim3((size_t)T_TOK * H_DIM / (256 * 8)), 256, 0, stream>>>(x, xb);
    router_kernel<<<dim3(T_TOK / 4), 256, 0, stream>>>(x, wg, logits, tk_e, tk_w, meta);
    scan_kernel<<<dim3(1), 64, 0, stream>>>(meta, slot_tok, slot_w);
    assign_kernel<<<dim3(T_TOK / 256), 256, 0, stream>>>(tk_e, tk_w, meta, slot_tok, slot_w);

    // ffn1: grid.x = F_DIM/64 = 112 (%8==0); ffn2: grid.x = H_DIM/128 = 16
    ffn1_kernel<<<dim3(F_DIM / 64, 16, E_NUM), 256, 0, stream>>>(xb, w1, w3, slot_tok, meta, hbuf);
    ffn2_kernel<<<dim3(H_DIM / 128, 16, E_NUM), 256, 0, stream>>>(hbuf, w2, slot_tok, slot_w, meta, out);
}

// Round 9
// 1510.796 us; speedup vs baseline: 1.1083x; 1.1083x over previous
//
#include <hip/hip_runtime.h>

#define T_TOK 2048
#define H_DIM 2048
#define F_DIM 7168
#define E_NUM 8
#define MAX_SLOTS 5120   // 4096 used slots + per-expert pad to 128

typedef __attribute__((ext_vector_type(8))) _Float16 f16x8;
typedef __attribute__((ext_vector_type(4))) float    f32x4;

// async global->LDS, 16B per lane; LDS dest wave-uniform base + lane*16
#define GLL(g, l) __builtin_amdgcn_global_load_lds(                          \
    (const __attribute__((address_space(1))) void*)(g),                      \
    (__attribute__((address_space(3))) void*)(l), 16, 0, 0)

// ---------------- small kernels ----------------

// fp32 -> fp16 bulk convert (hidden states only)
__global__ __launch_bounds__(256) void cvtx_kernel(const float* __restrict__ src,
                                                   _Float16* __restrict__ dst) {
    size_t i = ((size_t)blockIdx.x * 256 + threadIdx.x) * 8;
    float4 a = *(const float4*)(src + i);
    float4 b = *(const float4*)(src + i + 4);
    f16x8 h;
    h[0]=(_Float16)a.x; h[1]=(_Float16)a.y; h[2]=(_Float16)a.z; h[3]=(_Float16)a.w;
    h[4]=(_Float16)b.x; h[5]=(_Float16)b.y; h[6]=(_Float16)b.z; h[7]=(_Float16)b.w;
    *(f16x8*)(dst + i) = h;
}

__global__ __launch_bounds__(256) void router_kernel(
    const float* __restrict__ x, const float* __restrict__ wg,
    float* __restrict__ logits_out, int* __restrict__ tk_e,
    float* __restrict__ tk_w, int* __restrict__ meta) {
    int wave = threadIdx.x >> 6;
    int lane = threadIdx.x & 63;
    int t = blockIdx.x * 4 + wave;
    const float* xr = x + (size_t)t * H_DIM;

    float xv[32];
#pragma unroll
    for (int i = 0; i < 8; i++) {
        float4 v = *(const float4*)(xr + i * 256 + lane * 4);
        xv[i*4+0] = v.x; xv[i*4+1] = v.y; xv[i*4+2] = v.z; xv[i*4+3] = v.w;
    }
    float lg[E_NUM];
#pragma unroll
    for (int e = 0; e < E_NUM; e++) {
        const float* wr = wg + (size_t)e * H_DIM;
        float acc = 0.f;
#pragma unroll
        for (int i = 0; i < 8; i++) {
            float4 v = *(const float4*)(wr + i * 256 + lane * 4);
            acc += xv[i*4+0]*v.x + xv[i*4+1]*v.y + xv[i*4+2]*v.z + xv[i*4+3]*v.w;
        }
#pragma unroll
        for (int s = 32; s > 0; s >>= 1) acc += __shfl_xor(acc, s, 64);
        lg[e] = acc;
    }
    if (lane == 0) {
        float b0 = -3e38f, b1 = -3e38f; int i0 = 0, i1 = 0;
#pragma unroll
        for (int e = 0; e < E_NUM; e++) {
            float le = lg[e];
            if (le > b0)      { b1 = b0; i1 = i0; b0 = le; i0 = e; }
            else if (le > b1) { b1 = le; i1 = e; }
        }
        float w0 = 1.f / (1.f + __expf(b1 - b0));
        float w1v = 1.f - w0;
#pragma unroll
        for (int e = 0; e < E_NUM; e++) logits_out[(size_t)t * E_NUM + e] = lg[e];
        tk_e[t*2+0] = i0; tk_w[t*2+0] = w0;
        tk_e[t*2+1] = i1; tk_w[t*2+1] = w1v;
        atomicAdd(&meta[i0], 1);
        atomicAdd(&meta[i1], 1);
    }
}

// meta layout: [0..7]=cnt, [8..15]=cnt_pad128, [16..23]=base, [24..31]=fill
__global__ void scan_kernel(int* __restrict__ meta, int* __restrict__ slot_tok,
                            float* __restrict__ slot_w) {
    int lane = threadIdx.x;  // 64 threads
    int cnts[E_NUM], pads[E_NUM], bases[E_NUM];
    int run = 0;
#pragma unroll
    for (int e = 0; e < E_NUM; e++) {
        cnts[e] = meta[e];
        pads[e] = (cnts[e] + 127) & ~127;
        bases[e] = run;
        run += pads[e];
    }
    if (lane < E_NUM) { meta[8 + lane] = pads[lane]; meta[16 + lane] = bases[lane]; }
    for (int e = 0; e < E_NUM; e++)
        for (int i = cnts[e] + lane; i < pads[e]; i += 64) {
            slot_tok[bases[e] + i] = 0;
            slot_w[bases[e] + i] = 0.f;
        }
}

__global__ __launch_bounds__(256) void assign_kernel(
    const int* __restrict__ tk_e, const float* __restrict__ tk_w,
    int* __restrict__ meta, int* __restrict__ slot_tok, float* __restrict__ slot_w) {
    int t = blockIdx.x * 256 + threadIdx.x;
    if (t >= T_TOK) return;
#pragma unroll
    for (int k = 0; k < 2; k++) {
        int e = tk_e[t*2+k];
        int pos = atomicAdd(&meta[24 + e], 1);
        int s = meta[16 + e] + pos;
        slot_tok[s] = t;
        slot_w[s] = tk_w[t*2+k];
    }
}

// ============ fused-convert grouped GEMM, 128x128xK64, dbuf, 1 barrier/tile ============
// 4 waves 2Mx2N (64x64 each). A fp16 via GLL (source pre-swizzled, 1 tile ahead,
// counted vmcnt(12)); B fp32 reg-staged (loaded 1 tile ahead, cvt+swizzled ds_write
// after compute). LDS 64 KB -> 2 blocks/CU. __launch_bounds__(256,2): 256-reg
// combined cap (R8's no-bounds build got VGPR=64 -> prefetch fractured).

// ---------------- ffn1: B-rows 0..127 = interleaved w1/w3 (64 f-cols) ----------------
__global__ __launch_bounds__(256, 2) void ffn1_kernel(
    const _Float16* __restrict__ xb, const float* __restrict__ w1,
    const float* __restrict__ w3, const int* __restrict__ slot_tok,
    const int* __restrict__ meta, _Float16* __restrict__ hbuf) {
    int e = blockIdx.z;
    int cntpad = meta[8 + e];
    int mb = blockIdx.y;
    if (mb * 128 >= cntpad) return;
    int base = meta[16 + e];
    int nb = blockIdx.x;                 // 0..111, 64 f-cols each

    __shared__ _Float16 sA[2][128][64];  // 32 KB
    __shared__ _Float16 sB[2][128][64];  // 32 KB

    int tid  = threadIdx.x;
    int lane = tid & 63;
    int wave = tid >> 6;                 // 0..3
    int wm = wave >> 1, wn = wave & 1;   // 2(M) x 2(N), 64x64 per wave
    int lr  = lane & 15;
    int sg  = lane >> 4;
    int sw7 = lane & 7;
    int so0 = ((sg    ) ^ sw7) * 8;      // swizzled 16B-slot (half units), k-half 0
    int so1 = ((sg + 4) ^ sw7) * 8;      // k-half 1

    // ---- A staging (GLL): wave covers rows wave*32 + c*8 + rsub, source pre-swizzled
    int rsub = lane >> 3;
    int sl   = sw7 ^ rsub;
    const _Float16* aP[4];
#pragma unroll
    for (int c = 0; c < 4; c++) {
        int row = wave * 32 + c * 8 + rsub;
        int tok = slot_tok[base + mb * 128 + row];
        aP[c] = xb + (size_t)tok * H_DIM + sl * 8;
    }

    // ---- B staging (fp32 regs): brow = tid>>1, kh = tid&1 (32 floats each)
    // rows [q64*64 .. q64*64+31] = w1 f=nb*64+q64*32+sub, [+32..63] = w3 same f
    int brow = tid >> 1;
    int kh   = tid & 1;
    int q64  = brow >> 6;
    int sub  = brow & 63;
    const float* wsel = (sub < 32) ? w1 : w3;
    const float* bsrc = wsel + ((size_t)e * F_DIM + (size_t)nb * 64
                                + (size_t)q64 * 32 + (sub & 31)) * H_DIM + kh * 32;
    int bwr[4];
#pragma unroll
    for (int q = 0; q < 4; q++)
        bwr[q] = brow * 128 + (((kh * 4 + q) ^ (brow & 7)) * 16);

    f32x4 zero = {0.f, 0.f, 0.f, 0.f};
    f32x4 acc[4][4];
#pragma unroll
    for (int m = 0; m < 4; m++)
#pragma unroll
        for (int n = 0; n < 4; n++) acc[m][n] = zero;

    const int NT = H_DIM / 64;  // 32
    float4 brg[8];

    // ---- prologue: tile 0
#pragma unroll
    for (int q = 0; q < 8; q++) brg[q] = *(const float4*)(bsrc + q * 4);
#pragma unroll
    for (int c = 0; c < 4; c++) GLL(aP[c], &sA[0][wave * 32 + c * 8][0]);
    {
        char* sBc = (char*)&sB[0][0][0];
#pragma unroll
        for (int q = 0; q < 4; q++) {
            float4 a = brg[2*q], b = brg[2*q+1];
            f16x8 p;
            p[0]=(_Float16)a.x; p[1]=(_Float16)a.y; p[2]=(_Float16)a.z; p[3]=(_Float16)a.w;
            p[4]=(_Float16)b.x; p[5]=(_Float16)b.y; p[6]=(_Float16)b.z; p[7]=(_Float16)b.w;
            *(f16x8*)(void*)(sBc + bwr[q]) = p;
        }
    }
    asm volatile("s_waitcnt lgkmcnt(0)" ::: "memory");
    __builtin_amdgcn_s_barrier();

    for (int t = 0; t < NT; ++t) {
        int cur = t & 1, nxt = cur ^ 1;
        // issue next tile's loads FIRST (br then GLL), then counted wait on GLL(t)
        if (t + 1 < NT) {
            int k = (t + 1) * 64;
#pragma unroll
            for (int q = 0; q < 8; q++) brg[q] = *(const float4*)(bsrc + k + q * 4);
#pragma unroll
            for (int c = 0; c < 4; c++) GLL(aP[c] + k, &sA[nxt][wave * 32 + c * 8][0]);
            asm volatile("s_waitcnt vmcnt(12)" ::: "memory");   // GLL(t) complete
        } else {
            asm volatile("s_waitcnt vmcnt(0)" ::: "memory");
        }
        __builtin_amdgcn_sched_barrier(0);

        const _Float16* Ab = &sA[cur][wm * 64][0];
        const _Float16* Bb = &sB[cur][wn * 64][0];
        __builtin_amdgcn_s_setprio(1);
        {
            f16x8 a0[4], b0[4];
#pragma unroll
            for (int n = 0; n < 4; n++) b0[n] = *(const f16x8*)(const void*)(Bb + n * 1024 + lr * 64 + so0);
#pragma unroll
            for (int m = 0; m < 4; m++) a0[m] = *(const f16x8*)(const void*)(Ab + m * 1024 + lr * 64 + so0);
#pragma unroll
            for (int m = 0; m < 4; m++)
#pragma unroll
                for (int n = 0; n < 4; n++)
                    acc[m][n] = __builtin_amdgcn_mfma_f32_16x16x32_f16(a0[m], b0[n], acc[m][n], 0, 0, 0);
            f16x8 a1[4], b1[4];
#pragma unroll
            for (int n = 0; n < 4; n++) b1[n] = *(const f16x8*)(const void*)(Bb + n * 1024 + lr * 64 + so1);
#pragma unroll
            for (int m = 0; m < 4; m++) a1[m] = *(const f16x8*)(const void*)(Ab + m * 1024 + lr * 64 + so1);
#pragma unroll
            for (int m = 0; m < 4; m++)
#pragma unroll
                for (int n = 0; n < 4; n++)
                    acc[m][n] = __builtin_amdgcn_mfma_f32_16x16x32_f16(a1[m], b1[n], acc[m][n], 0, 0, 0);
        }
        __builtin_amdgcn_s_setprio(0);
        __builtin_amdgcn_sched_barrier(0);   // keep cvt/ds_write AFTER the MFMAs

        if (t + 1 < NT) {                    // write B(t+1) (compiler waits br loads)
            char* sBc = (char*)&sB[nxt][0][0];
#pragma unroll
            for (int q = 0; q < 4; q++) {
                float4 a = brg[2*q], b = brg[2*q+1];
                f16x8 p;
                p[0]=(_Float16)a.x; p[1]=(_Float16)a.y; p[2]=(_Float16)a.z; p[3]=(_Float16)a.w;
                p[4]=(_Float16)b.x; p[5]=(_Float16)b.y; p[6]=(_Float16)b.z; p[7]=(_Float16)b.w;
                *(f16x8*)(void*)(sBc + bwr[q]) = p;
            }
        }
        asm volatile("s_waitcnt lgkmcnt(0)" ::: "memory");
        __builtin_amdgcn_s_barrier();
    }

    // epilogue: pairs (n, n+2) = (w1, w3) same f; f = nb*64 + wn*32 + n*16 + lr
    int fb = nb * 64 + wn * 32;
#pragma unroll
    for (int m = 0; m < 4; m++) {
#pragma unroll
        for (int j = 0; j < 4; j++) {
            int re = mb * 128 + wm * 64 + m * 16 + sg * 4 + j;
            size_t srow = (size_t)(base + re) * F_DIM;
#pragma unroll
            for (int p = 0; p < 2; p++) {
                float a1v = acc[m][p][j], a3v = acc[m][p + 2][j];
                float hv = a1v * a3v / (1.f + __expf(-a1v));
                hbuf[srow + fb + p * 16 + lr] = (_Float16)hv;
            }
        }
    }
}

// ---------------- ffn2: A = hbuf fp16 (GLL), B = w2 fp32 reg-staged ----------------
__global__ __launch_bounds__(256, 2) void ffn2_kernel(
    const _Float16* __restrict__ hbuf, const float* __restrict__ w2,
    const int* __restrict__ slot_tok, const float* __restrict__ slot_w,
    const int* __restrict__ meta, float* __restrict__ out) {
    int e = blockIdx.z;
    int cntpad = meta[8 + e];
    int mb = blockIdx.y;
    if (mb * 128 >= cntpad) return;
    int base = meta[16 + e];
    int nb = blockIdx.x;                 // 0..15, 128 H-cols each

    __shared__ _Float16 sA[2][128][64];
    __shared__ _Float16 sB[2][128][64];

    int tid  = threadIdx.x;
    int lane = tid & 63;
    int wave = tid >> 6;
    int wm = wave >> 1, wn = wave & 1;
    int lr  = lane & 15;
    int sg  = lane >> 4;
    int sw7 = lane & 7;
    int so0 = ((sg    ) ^ sw7) * 8;
    int so1 = ((sg + 4) ^ sw7) * 8;

    int rsub = lane >> 3;
    int sl   = sw7 ^ rsub;
    const _Float16* aP[4];
#pragma unroll
    for (int c = 0; c < 4; c++) {
        int row = wave * 32 + c * 8 + rsub;
        aP[c] = hbuf + (size_t)(base + mb * 128 + row) * F_DIM + sl * 8;
    }

    int brow = tid >> 1;
    int kh   = tid & 1;
    const float* bsrc = w2 + ((size_t)e * H_DIM + (size_t)nb * 128 + brow) * F_DIM + kh * 32;
    int bwr[4];
#pragma unroll
    for (int q = 0; q < 4; q++)
        bwr[q] = brow * 128 + (((kh * 4 + q) ^ (brow & 7)) * 16);

    f32x4 zero = {0.f, 0.f, 0.f, 0.f};
    f32x4 acc[4][4];
#pragma unroll
    for (int m = 0; m < 4; m++)
#pragma unroll
        for (int n = 0; n < 4; n++) acc[m][n] = zero;

    const int NT = F_DIM / 64;  // 112
    float4 brg[8];

#pragma unroll
    for (int q = 0; q < 8; q++) brg[q] = *(const float4*)(bsrc + q * 4);
#pragma unroll
    for (int c = 0; c < 4; c++) GLL(aP[c], &sA[0][wave * 32 + c * 8][0]);
    {
        char* sBc = (char*)&sB[0][0][0];
#pragma unroll
        for (int q = 0; q < 4; q++) {
            float4 a = brg[2*q], b = brg[2*q+1];
            f16x8 p;
            p[0]=(_Float16)a.x; p[1]=(_Float16)a.y; p[2]=(_Float16)a.z; p[3]=(_Float16)a.w;
            p[4]=(_Float16)b.x; p[5]=(_Float16)b.y; p[6]=(_Float16)b.z; p[7]=(_Float16)b.w;
            *(f16x8*)(void*)(sBc + bwr[q]) = p;
        }
    }
    asm volatile("s_waitcnt lgkmcnt(0)" ::: "memory");
    __builtin_amdgcn_s_barrier();

    for (int t = 0; t < NT; ++t) {
        int cur = t & 1, nxt = cur ^ 1;
        if (t + 1 < NT) {
            int k = (t + 1) * 64;
#pragma unroll
            for (int q = 0; q < 8; q++) brg[q] = *(const float4*)(bsrc + k + q * 4);
#pragma unroll
            for (int c = 0; c < 4; c++) GLL(aP[c] + k, &sA[nxt][wave * 32 + c * 8][0]);
            asm volatile("s_waitcnt vmcnt(12)" ::: "memory");
        } else {
            asm volatile("s_waitcnt vmcnt(0)" ::: "memory");
        }
        __builtin_amdgcn_sched_barrier(0);

        const _Float16* Ab = &sA[cur][wm * 64][0];
        const _Float16* Bb = &sB[cur][wn * 64][0];
        __builtin_amdgcn_s_setprio(1);
        {
            f16x8 a0[4], b0[4];
#pragma unroll
            for (int n = 0; n < 4; n++) b0[n] = *(const f16x8*)(const void*)(Bb + n * 1024 + lr * 64 + so0);
#pragma unroll
            for (int m = 0; m < 4; m++) a0[m] = *(const f16x8*)(const void*)(Ab + m * 1024 + lr * 64 + so0);
#pragma unroll
            for (int m = 0; m < 4; m++)
#pragma unroll
                for (int n = 0; n < 4; n++)
                    acc[m][n] = __builtin_amdgcn_mfma_f32_16x16x32_f16(a0[m], b0[n], acc[m][n], 0, 0, 0);
            f16x8 a1[4], b1[4];
#pragma unroll
            for (int n = 0; n < 4; n++) b1[n] = *(const f16x8*)(const void*)(Bb + n * 1024 + lr * 64 + so1);
#pragma unroll
            for (int m = 0; m < 4; m++) a1[m] = *(const f16x8*)(const void*)(Ab + m * 1024 + lr * 64 + so1);
#pragma unroll
            for (int m = 0; m < 4; m++)
#pragma unroll
                for (int n = 0; n < 4; n++)
                    acc[m][n] = __builtin_amdgcn_mfma_f32_16x16x32_f16(a1[m], b1[n], acc[m][n], 0, 0, 0);
        }
        __builtin_amdgcn_s_setprio(0);
        __builtin_amdgcn_sched_barrier(0);

        if (t + 1 < NT) {
            char* sBc = (char*)&sB[nxt][0][0];
#pragma unroll
            for (int q = 0; q < 4; q++) {
                float4 a = brg[2*q], b = brg[2*q+1];
                f16x8 p;
                p[0]=(_Float16)a.x; p[1]=(_Float16)a.y; p[2]=(_Float16)a.z; p[3]=(_Float16)a.w;
                p[4]=(_Float16)b.x; p[5]=(_Float16)b.y; p[6]=(_Float16)b.z; p[7]=(_Float16)b.w;
                *(f16x8*)(void*)(sBc + bwr[q]) = p;
            }
        }
        asm volatile("s_waitcnt lgkmcnt(0)" ::: "memory");
        __builtin_amdgcn_s_barrier();
    }

    int row0 = mb * 128 + wm * 64;
    int col0 = nb * 128 + wn * 64;
#pragma unroll
    for (int m = 0; m < 4; m++) {
        int rbw = row0 + m * 16 + sg * 4;
        int toks[4]; float wts[4];
#pragma unroll
        for (int j = 0; j < 4; j++) {
            int s = base + rbw + j;
            toks[j] = slot_tok[s];
            wts[j]  = slot_w[s];
        }
#pragma unroll
        for (int n = 0; n < 4; n++) {
            int col = col0 + n * 16 + lr;
            f32x4 v = acc[m][n];
#pragma unroll
            for (int j = 0; j < 4; j++)
                atomicAdd(&out[(size_t)toks[j] * H_DIM + col], v[j] * wts[j]);
        }
    }
}

// ---------------- launcher ----------------
extern "C" void kernel_launch(void* const* d_in, const int* in_sizes, int n_in,
                              void* d_out, int out_size, void* d_ws, size_t ws_size,
                              hipStream_t stream) {
    const float* x  = (const float*)d_in[0];
    const float* wg = (const float*)d_in[1];
    const float* w1 = (const float*)d_in[2];
    const float* w3 = (const float*)d_in[3];
    const float* w2 = (const float*)d_in[4];
    float* out = (float*)d_out;
    float* logits = out + (size_t)T_TOK * H_DIM;

    char* ws = (char*)d_ws;
    _Float16* hbuf = (_Float16*)ws;                       // 70 MiB
    _Float16* xb   = hbuf + (size_t)MAX_SLOTS * F_DIM;    // 8 MiB
    char* p = (char*)(xb + (size_t)T_TOK * H_DIM);
    int*   slot_tok = (int*)p;   p += MAX_SLOTS * 4;
    float* slot_w   = (float*)p; p += MAX_SLOTS * 4;
    int*   tk_e     = (int*)p;   p += T_TOK * 2 * 4;
    float* tk_w     = (float*)p; p += T_TOK * 2 * 4;
    int*   meta     = (int*)p;   // 32 ints

    hipMemsetAsync(d_out, 0, (size_t)out_size * sizeof(float), stream);
    hipMemsetAsync(meta, 0, 32 * sizeof(int), stream);

    cvtx_kernel<<<dim3((size_t)T_TOK * H_DIM / (256 * 8)), 256, 0, stream>>>(x, xb);
    router_kernel<<<dim3(T_TOK / 4), 256, 0, stream>>>(x, wg, logits, tk_e, tk_w, meta);
    scan_kernel<<<dim3(1), 64, 0, stream>>>(meta, slot_tok, slot_w);
    assign_kernel<<<dim3(T_TOK / 256), 256, 0, stream>>>(tk_e, tk_w, meta, slot_tok, slot_w);

    // ffn1: grid.x = F_DIM/64 = 112 (%8==0); ffn2: grid.x = H_DIM/128 = 16
    ffn1_kernel<<<dim3(F_DIM / 64, 16, E_NUM), 256, 0, stream>>>(xb, w1, w3, slot_tok, meta, hbuf);
    ffn2_kernel<<<dim3(H_DIM / 128, 16, E_NUM), 256, 0, stream>>>(hbuf, w2, slot_tok, slot_w, meta, out);
}